// Round 8
// baseline (213.829 us; speedup 1.0000x reference)
//
#include <hip/hip_runtime.h>
#include <stdint.h>

#define NGT 8000
#define NSAMP 4000
#define QT 3        // queries per thread (register tile)
#define QB 768      // queries per block (256 threads * QT)
#define CH 384      // scanned-points chunk per blockIdx.z (multiple of 4)

typedef float f2 __attribute__((ext_vector_type(2)));

// forced packed fp32 FMA (VOP3P) — compiler won't emit it on its own (R6 evidence)
__device__ __forceinline__ f2 pk_fma(f2 a, f2 b, f2 c){
  f2 d;
  asm("v_pk_fma_f32 %0, %1, %2, %3" : "=v"(d) : "v"(a), "v"(b), "v"(c));
  return d;
}

struct Params {
  const float* gt;        // (8000,3)
  const float* gtn;       // (8000,3)
  const float* pred[3];   // (v,3)
  const float* bef[3];    // (v,3)
  const int*   edges[3];  // (3v,2)
  const int*   faces[3];  // (2v,3)
  const int*   lap[3];    // (v,10)
  float* S[3];            // (4000,3) sampled surface points
  unsigned int* mb1[3];        // (8000) ordered-float min bits (dist1)
  unsigned long long* mb2a[3]; // (v) packed (ordered dist << 32 | gt idx) for pred queries
  unsigned int* mb2b[3];       // (4000) ordered-float min bits for sample queries
  float* acc;             // per mesh i: [8i]=sum_d1 [8i+1]=sum_d2 [8i+2]=sum|dot| [8i+3]=edge_sq [8i+4]=lap_sq [8i+5]=move_sq
  unsigned int* counter;  // finish_kernel block-completion counter
  unsigned int* init_base;// = (u32*)d_ws
  int init_words;         // words to initialize (first 64 -> 0, rest -> 0xFF)
  int v[3], M[3], E[3], F[3];
  int z1, z2;             // chunk counts: dist1 z in [0,z1); dist2-pred [z1,z1+z2); dist2-samp [z1+z2,z1+2*z2)
};

// ---- ordered-float <-> uint (monotone, atomicMin-compatible) ----
__device__ __forceinline__ unsigned int ford(float f){
  unsigned int b = __float_as_uint(f);
  return b ^ ((b >> 31) ? 0xFFFFFFFFu : 0x80000000u);
}
__device__ __forceinline__ float funord(unsigned int u){
  unsigned int b = u ^ ((u >> 31) ? 0x80000000u : 0xFFFFFFFFu);
  return __uint_as_float(b);
}

// ---------------- threefry2x32 (exact JAX) ----------------
__device__ __forceinline__ uint32_t rotl32(uint32_t x, int d){ return (x<<d)|(x>>(32-d)); }

__device__ __forceinline__ void tf2x32(uint32_t k0, uint32_t k1, uint32_t c0, uint32_t c1,
                                       uint32_t& o0, uint32_t& o1){
  uint32_t ks2 = k0 ^ k1 ^ 0x1BD11BDAu;
  uint32_t x0 = c0 + k0, x1 = c1 + k1;
  x0+=x1; x1=rotl32(x1,13); x1^=x0;
  x0+=x1; x1=rotl32(x1,15); x1^=x0;
  x0+=x1; x1=rotl32(x1,26); x1^=x0;
  x0+=x1; x1=rotl32(x1, 6); x1^=x0;
  x0+=k1; x1+=ks2+1u;
  x0+=x1; x1=rotl32(x1,17); x1^=x0;
  x0+=x1; x1=rotl32(x1,29); x1^=x0;
  x0+=x1; x1=rotl32(x1,16); x1^=x0;
  x0+=x1; x1=rotl32(x1,24); x1^=x0;
  x0+=ks2; x1+=k0+2u;
  x0+=x1; x1=rotl32(x1,13); x1^=x0;
  x0+=x1; x1=rotl32(x1,15); x1^=x0;
  x0+=x1; x1=rotl32(x1,26); x1^=x0;
  x0+=x1; x1=rotl32(x1, 6); x1^=x0;
  x0+=k0; x1+=k1+3u;
  x0+=x1; x1=rotl32(x1,17); x1^=x0;
  x0+=x1; x1=rotl32(x1,29); x1^=x0;
  x0+=x1; x1=rotl32(x1,16); x1^=x0;
  x0+=x1; x1=rotl32(x1,24); x1^=x0;
  x0+=k1; x1+=ks2+4u;
  x0+=x1; x1=rotl32(x1,13); x1^=x0;
  x0+=x1; x1=rotl32(x1,15); x1^=x0;
  x0+=x1; x1=rotl32(x1,26); x1^=x0;
  x0+=x1; x1=rotl32(x1, 6); x1^=x0;
  x0+=ks2; x1+=k0+5u;
  o0=x0; o1=x1;
}

__device__ __forceinline__ uint32_t rbits(uint32_t k0, uint32_t k1, uint32_t idx, uint32_t total){
  uint32_t half = total>>1, o0, o1;
  if (idx < half){ tf2x32(k0,k1, idx, idx+half, o0, o1); return o0; }
  tf2x32(k0,k1, idx-half, idx, o0, o1); return o1;
}

// ---------------- A: init workspace (z=0,y=0) + sample surface points (z=1) ----------------
__global__ __launch_bounds__(256) void prep_kernel(Params p){
  if (blockIdx.z == 0){
    if (blockIdx.y != 0) return;
    int wdi = blockIdx.x*256 + threadIdx.x;
    if (wdi < p.init_words)
      p.init_base[wdi] = (wdi < 64) ? 0u : 0xFFFFFFFFu;
    return;
  }
  int i = blockIdx.y;
  int s = blockIdx.x*256 + threadIdx.x;
  if (s >= NSAMP) return;
  uint32_t bk0, bk1; tf2x32(0u, 42u, 0u, (uint32_t)i, bk0, bk1);
  uint32_t a0,b0,a1,b1;
  tf2x32(bk0,bk1, 0u,2u, a0,b0);
  tf2x32(bk0,bk1, 1u,3u, a1,b1);
  uint32_t fb = rbits(a0,a1,(uint32_t)s, NSAMP);
  uint32_t fidx = fb % (uint32_t)p.F[i];
  uint32_t u0b = rbits(b0,b1, 2u*(uint32_t)s,    2u*NSAMP);
  uint32_t u1b = rbits(b0,b1, 2u*(uint32_t)s+1u, 2u*NSAMP);
  float u0 = __uint_as_float((u0b>>9)|0x3F800000u) - 1.0f;
  float u1 = __uint_as_float((u1b>>9)|0x3F800000u) - 1.0f;
  float r1 = sqrtf(u0);
  float w0 = 1.0f - r1, w1 = r1*(1.0f-u1), w2 = r1*u1;
  const int* f = p.faces[i] + 3*(int)fidx;
  const float* pr = p.pred[i];
  int va=f[0], vb=f[1], vc=f[2];
  float* dst = p.S[i] + 3*s;
  dst[0] = w0*pr[3*va+0] + w1*pr[3*vb+0] + w2*pr[3*vc+0];
  dst[1] = w0*pr[3*va+1] + w1*pr[3*vb+1] + w2*pr[3*vc+1];
  dst[2] = w0*pr[3*va+2] + w1*pr[3*vb+2] + w2*pr[3*vc+2];
}

// ---------------- B: fused chamfer, 3 roles, chunked + register-tiled + packed fp32 ----------------
// logical point set P = pred (v pts) ++ samples (4000 pts).
// z in [0,z1)        : dist1      — queries = gt (8000),  scan P chunk z
// z in [z1,z1+z2)    : dist2-pred — queries = pred (v),   scan gt chunk, track argmin
// z in [z1+z2,z1+2z2): dist2-samp — queries = S (4000),   scan gt chunk, min only
__global__ __launch_bounds__(256) void chamfer_kernel(Params p){
  int i = blockIdx.y;
  int v = p.v[i];
  int M = p.M[i];
  int z = blockIdx.z;
  __shared__ __align__(16) float xs[CH], ys[CH], zs[CH], ws[CH];
  int t = threadIdx.x;
  int qbase = blockIdx.x*QB;

  if (z < p.z1){
    // ---- dist1: queries = gt, scan one P chunk ----
    if (qbase >= NGT) return;
    int c0 = z*CH;
    if (c0 >= M) return;
    int c1 = min(M, c0+CH);
    int lim = c1 - c0;

    for (int jj=t; jj<lim; jj+=256){
      int j = c0 + jj;
      const float* src = (j < v) ? (p.pred[i] + 3*j) : (p.S[i] + 3*(j-v));
      float x=src[0], y=src[1], zz=src[2];
      xs[jj]=x; ys[jj]=y; zs[jj]=zz; ws[jj]=x*x+y*y+zz*zz;
    }

    f2 qx[QT], qy[QT], qz[QT];
    float qs[QT];
    f2 bl[QT], bh[QT];
    #pragma unroll
    for (int k=0;k<QT;k++){
      int q = qbase + t + k*256;
      float x=0.f,y=0.f,zz=0.f;
      if (q < NGT){ x=p.gt[3*q]; y=p.gt[3*q+1]; zz=p.gt[3*q+2]; }
      qs[k]=x*x+y*y+zz*zz;
      qx[k]=(f2){-2.f*x,-2.f*x}; qy[k]=(f2){-2.f*y,-2.f*y}; qz[k]=(f2){-2.f*zz,-2.f*zz};
      bl[k]=(f2){3.4e38f,3.4e38f}; bh[k]=(f2){3.4e38f,3.4e38f};
    }
    __syncthreads();

    int lim4 = lim & ~3;
    const float4* X4 = (const float4*)xs;
    const float4* Y4 = (const float4*)ys;
    const float4* Z4 = (const float4*)zs;
    const float4* W4 = (const float4*)ws;
    #pragma unroll 2
    for (int k4=0; k4<(lim4>>2); k4++){
      float4 X = X4[k4], Y = Y4[k4], Z = Z4[k4], W = W4[k4];
      f2 Xl={X.x,X.y}, Xh={X.z,X.w};
      f2 Yl={Y.x,Y.y}, Yh={Y.z,Y.w};
      f2 Zl={Z.x,Z.y}, Zh={Z.z,Z.w};
      f2 Wl={W.x,W.y}, Wh={W.z,W.w};
      #pragma unroll
      for (int q=0;q<QT;q++){
        f2 dl = pk_fma(Xl,qx[q], pk_fma(Yl,qy[q], pk_fma(Zl,qz[q], Wl)));
        f2 dh = pk_fma(Xh,qx[q], pk_fma(Yh,qy[q], pk_fma(Zh,qz[q], Wh)));
        bl[q] = __builtin_elementwise_min(bl[q], dl);
        bh[q] = __builtin_elementwise_min(bh[q], dh);
      }
    }
    for (int k=lim4; k<lim; k++){
      float X=xs[k], Y=ys[k], Z=zs[k], W=ws[k];
      #pragma unroll
      for (int q=0;q<QT;q++){
        float d = fmaf(X,qx[q].x, fmaf(Y,qy[q].x, fmaf(Z,qz[q].x, W)));
        bl[q].x = fminf(bl[q].x, d);
      }
    }
    #pragma unroll
    for (int k=0;k<QT;k++){
      int q = qbase + t + k*256;
      if (q < NGT){
        float b = fminf(fminf(bl[k].x, bl[k].y), fminf(bh[k].x, bh[k].y));
        atomicMin(&p.mb1[i][q], ford(b + qs[k]));
      }
    }
  } else if (z < p.z1 + p.z2){
    // ---- dist2-pred: queries = pred, scan one gt chunk, argmin tracked ----
    if (qbase >= v) return;
    int c0 = (z - p.z1)*CH;
    int c1 = min(NGT, c0+CH);
    int lim = c1 - c0;

    for (int jj=t; jj<lim; jj+=256){
      int j = c0 + jj;
      float x=p.gt[3*j], y=p.gt[3*j+1], zz=p.gt[3*j+2];
      xs[jj]=x; ys[jj]=y; zs[jj]=zz; ws[jj]=x*x+y*y+zz*zz;
    }

    f2 qx[QT], qy[QT], qz[QT];
    float qs[QT], best[QT];
    int bidx[QT];
    #pragma unroll
    for (int k=0;k<QT;k++){
      int q = qbase + t + k*256;
      float x=0.f,y=0.f,zz=0.f;
      if (q < v){
        const float* src = p.pred[i] + 3*q;
        x=src[0]; y=src[1]; zz=src[2];
      }
      qs[k]=x*x+y*y+zz*zz;
      qx[k]=(f2){-2.f*x,-2.f*x}; qy[k]=(f2){-2.f*y,-2.f*y}; qz[k]=(f2){-2.f*zz,-2.f*zz};
      best[k]=3.4e38f; bidx[k]=0;
    }
    __syncthreads();

    int lim4 = lim & ~3;
    const float4* X4 = (const float4*)xs;
    const float4* Y4 = (const float4*)ys;
    const float4* Z4 = (const float4*)zs;
    const float4* W4 = (const float4*)ws;
    for (int k4=0; k4<(lim4>>2); k4++){
      float4 X = X4[k4], Y = Y4[k4], Z = Z4[k4], W = W4[k4];
      f2 Xl={X.x,X.y}, Xh={X.z,X.w};
      f2 Yl={Y.x,Y.y}, Yh={Y.z,Y.w};
      f2 Zl={Z.x,Z.y}, Zh={Z.z,Z.w};
      f2 Wl={W.x,W.y}, Wh={W.z,W.w};
      int kb = c0 + (k4<<2);
      #pragma unroll
      for (int q=0;q<QT;q++){
        f2 dl = pk_fma(Xl,qx[q], pk_fma(Yl,qy[q], pk_fma(Zl,qz[q], Wl)));
        f2 dh = pk_fma(Xh,qx[q], pk_fma(Yh,qy[q], pk_fma(Zh,qz[q], Wh)));
        if (dl.x < best[q]){ best[q]=dl.x; bidx[q]=kb;   }  // sequential: first min
        if (dl.y < best[q]){ best[q]=dl.y; bidx[q]=kb+1; }
        if (dh.x < best[q]){ best[q]=dh.x; bidx[q]=kb+2; }
        if (dh.y < best[q]){ best[q]=dh.y; bidx[q]=kb+3; }
      }
    }
    for (int k=lim4; k<lim; k++){
      float X=xs[k], Y=ys[k], Z=zs[k], W=ws[k];
      #pragma unroll
      for (int q=0;q<QT;q++){
        float d = fmaf(X,qx[q].x, fmaf(Y,qy[q].x, fmaf(Z,qz[q].x, W)));
        if (d < best[q]){ best[q]=d; bidx[q]=c0+k; }
      }
    }
    #pragma unroll
    for (int k=0;k<QT;k++){
      int q = qbase + t + k*256;
      if (q < v){
        unsigned long long pk = ((unsigned long long)ford(best[k]+qs[k])<<32) | (unsigned int)bidx[k];
        atomicMin(&p.mb2a[i][q], pk);   // equal dist -> smaller gt idx = first occurrence
      }
    }
  } else {
    // ---- dist2-samp: queries = S (their argmin is never consumed) ----
    if (qbase >= NSAMP) return;
    int c0 = (z - p.z1 - p.z2)*CH;
    int c1 = min(NGT, c0+CH);
    int lim = c1 - c0;

    for (int jj=t; jj<lim; jj+=256){
      int j = c0 + jj;
      float x=p.gt[3*j], y=p.gt[3*j+1], zz=p.gt[3*j+2];
      xs[jj]=x; ys[jj]=y; zs[jj]=zz; ws[jj]=x*x+y*y+zz*zz;
    }

    f2 qx[QT], qy[QT], qz[QT];
    float qs[QT];
    f2 bl[QT], bh[QT];
    #pragma unroll
    for (int k=0;k<QT;k++){
      int q = qbase + t + k*256;
      float x=0.f,y=0.f,zz=0.f;
      if (q < NSAMP){
        const float* src = p.S[i] + 3*q;
        x=src[0]; y=src[1]; zz=src[2];
      }
      qs[k]=x*x+y*y+zz*zz;
      qx[k]=(f2){-2.f*x,-2.f*x}; qy[k]=(f2){-2.f*y,-2.f*y}; qz[k]=(f2){-2.f*zz,-2.f*zz};
      bl[k]=(f2){3.4e38f,3.4e38f}; bh[k]=(f2){3.4e38f,3.4e38f};
    }
    __syncthreads();

    int lim4 = lim & ~3;
    const float4* X4 = (const float4*)xs;
    const float4* Y4 = (const float4*)ys;
    const float4* Z4 = (const float4*)zs;
    const float4* W4 = (const float4*)ws;
    #pragma unroll 2
    for (int k4=0; k4<(lim4>>2); k4++){
      float4 X = X4[k4], Y = Y4[k4], Z = Z4[k4], W = W4[k4];
      f2 Xl={X.x,X.y}, Xh={X.z,X.w};
      f2 Yl={Y.x,Y.y}, Yh={Y.z,Y.w};
      f2 Zl={Z.x,Z.y}, Zh={Z.z,Z.w};
      f2 Wl={W.x,W.y}, Wh={W.z,W.w};
      #pragma unroll
      for (int q=0;q<QT;q++){
        f2 dl = pk_fma(Xl,qx[q], pk_fma(Yl,qy[q], pk_fma(Zl,qz[q], Wl)));
        f2 dh = pk_fma(Xh,qx[q], pk_fma(Yh,qy[q], pk_fma(Zh,qz[q], Wh)));
        bl[q] = __builtin_elementwise_min(bl[q], dl);
        bh[q] = __builtin_elementwise_min(bh[q], dh);
      }
    }
    for (int k=lim4; k<lim; k++){
      float X=xs[k], Y=ys[k], Z=zs[k], W=ws[k];
      #pragma unroll
      for (int q=0;q<QT;q++){
        float d = fmaf(X,qx[q].x, fmaf(Y,qy[q].x, fmaf(Z,qz[q].x, W)));
        bl[q].x = fminf(bl[q].x, d);
      }
    }
    #pragma unroll
    for (int k=0;k<QT;k++){
      int q = qbase + t + k*256;
      if (q < NSAMP){
        float b = fminf(fminf(bl[k].x, bl[k].y), fminf(bh[k].x, bh[k].y));
        atomicMin(&p.mb2b[i][q], ford(b + qs[k]));
      }
    }
  }
}

// ---------------- C: all reductions + losses + last-block finalize ----------------
// z=0: dist2 sum over M; z=1: dist1 sum over NGT; z=2: edge+normal over E; z=3: lap+move over v
__global__ __launch_bounds__(256) void finish_kernel(Params p, float* out){
  __shared__ float red[256];
  int i = blockIdx.y;
  int z = blockIdx.z;
  int tid = threadIdx.x;
  int gidx = blockIdx.x*256 + tid;

  if (z == 0){
    int M = p.M[i], v = p.v[i];
    float val = 0.f;
    if (gidx < M){
      if (gidx < v) val = funord((unsigned int)(p.mb2a[i][gidx]>>32));
      else          val = funord(p.mb2b[i][gidx-v]);
    }
    red[tid] = val; __syncthreads();
    for (int s=128;s>0;s>>=1){ if (tid<s) red[tid]+=red[tid+s]; __syncthreads(); }
    if (tid==0 && red[0]!=0.f) atomicAdd(&p.acc[8*i+1], red[0]);
  } else if (z == 1){
    float val = 0.f;
    if (gidx < NGT) val = funord(p.mb1[i][gidx]);
    red[tid] = val; __syncthreads();
    for (int s=128;s>0;s>>=1){ if (tid<s) red[tid]+=red[tid+s]; __syncthreads(); }
    if (tid==0 && red[0]!=0.f) atomicAdd(&p.acc[8*i+0], red[0]);
  } else if (z == 2){
    int E = p.E[i];
    float sq = 0.f, ad = 0.f;
    if (gidx < E){
      int e0 = p.edges[i][2*gidx], e1 = p.edges[i][2*gidx+1];
      const float* pr = p.pred[i];
      float dx = pr[3*e0+0]-pr[3*e1+0];
      float dy = pr[3*e0+1]-pr[3*e1+1];
      float dz = pr[3*e0+2]-pr[3*e1+2];
      sq = dx*dx+dy*dy+dz*dz;
      float inv = 1.0f / fmaxf(sqrtf(sq), 1e-12f);
      int g = (int)(unsigned int)p.mb2a[i][e0];   // argmin gt index (low 32 bits)
      float nx = p.gtn[3*g+0], ny = p.gtn[3*g+1], nz = p.gtn[3*g+2];
      float invg = 1.0f / fmaxf(sqrtf(nx*nx+ny*ny+nz*nz), 1e-12f);
      ad = fabsf((dx*nx+dy*ny+dz*nz)*inv*invg);
    }
    red[tid] = ad; __syncthreads();
    for (int s=128;s>0;s>>=1){ if (tid<s) red[tid]+=red[tid+s]; __syncthreads(); }
    if (tid==0 && red[0]!=0.f) atomicAdd(&p.acc[8*i+2], red[0]);
    __syncthreads();
    red[tid] = sq; __syncthreads();
    for (int s=128;s>0;s>>=1){ if (tid<s) red[tid]+=red[tid+s]; __syncthreads(); }
    if (tid==0 && red[0]!=0.f) atomicAdd(&p.acc[8*i+3], red[0]);
  } else {
    int v = p.v[i];
    float lsq = 0.f, msq = 0.f;
    if (gidx < v){
      const int* L = p.lap[i] + 10*gidx;
      const float* B = p.bef[i];
      const float* R = p.pred[i];
      float cnt = (float)L[9];
      float sb0=0,sb1=0,sb2=0, sp0=0,sp1=0,sp2=0;
      #pragma unroll
      for (int k=0;k<8;k++){
        int id = L[k];
        if (id >= 0){
          sb0 += B[3*id+0]; sb1 += B[3*id+1]; sb2 += B[3*id+2];
          sp0 += R[3*id+0]; sp1 += R[3*id+1]; sp2 += R[3*id+2];
        }
      }
      float lb0 = B[3*gidx+0] - sb0/cnt, lb1 = B[3*gidx+1] - sb1/cnt, lb2 = B[3*gidx+2] - sb2/cnt;
      float lp0 = R[3*gidx+0] - sp0/cnt, lp1 = R[3*gidx+1] - sp1/cnt, lp2 = R[3*gidx+2] - sp2/cnt;
      float d0=lb0-lp0, d1=lb1-lp1, d2=lb2-lp2;
      lsq = d0*d0+d1*d1+d2*d2;
      float m0=B[3*gidx+0]-R[3*gidx+0], m1=B[3*gidx+1]-R[3*gidx+1], m2=B[3*gidx+2]-R[3*gidx+2];
      msq = m0*m0+m1*m1+m2*m2;
    }
    red[tid] = lsq; __syncthreads();
    for (int s=128;s>0;s>>=1){ if (tid<s) red[tid]+=red[tid+s]; __syncthreads(); }
    if (tid==0 && red[0]!=0.f) atomicAdd(&p.acc[8*i+4], red[0]);
    __syncthreads();
    red[tid] = msq; __syncthreads();
    for (int s=128;s>0;s>>=1){ if (tid<s) red[tid]+=red[tid+s]; __syncthreads(); }
    if (tid==0 && red[0]!=0.f) atomicAdd(&p.acc[8*i+5], red[0]);
  }

  __syncthreads();
  if (tid == 0){
    __threadfence();
    unsigned int total = gridDim.x*gridDim.y*gridDim.z;
    unsigned int old = atomicAdd(p.counter, 1u);
    if (old == total-1){
      __threadfence();
      const float CHAMW[3] = {3000.0f, 3000.0f, 3000.0f};
      const float LAPC[3]  = {0.2f, 1.0f, 1.0f};
      float loss = 0.0f;
      for (int m=0;m<3;m++){
        float a0 = __hip_atomic_load(&p.acc[8*m+0], __ATOMIC_RELAXED, __HIP_MEMORY_SCOPE_AGENT);
        float a1 = __hip_atomic_load(&p.acc[8*m+1], __ATOMIC_RELAXED, __HIP_MEMORY_SCOPE_AGENT);
        float a2 = __hip_atomic_load(&p.acc[8*m+2], __ATOMIC_RELAXED, __HIP_MEMORY_SCOPE_AGENT);
        float a3 = __hip_atomic_load(&p.acc[8*m+3], __ATOMIC_RELAXED, __HIP_MEMORY_SCOPE_AGENT);
        float a4 = __hip_atomic_load(&p.acc[8*m+4], __ATOMIC_RELAXED, __HIP_MEMORY_SCOPE_AGENT);
        float a5 = __hip_atomic_load(&p.acc[8*m+5], __ATOMIC_RELAXED, __HIP_MEMORY_SCOPE_AGENT);
        float ch = CHAMW[m]*(a0/(float)NGT + 0.55f*a1/(float)p.M[m]);
        float nl = a2/(float)p.E[m];
        float el = a3/(float)p.E[m];
        float ll = LAPC[m]*a4/(float)p.v[m];
        float ml = (m>0) ? LAPC[m]*a5/(float)p.v[m] : 0.0f;
        loss += ch + 1500.0f*ll + 50.0f*ml + 359.0f*el + 0.5f*nl;
      }
      out[0] = loss;
    }
  }
}

extern "C" void kernel_launch(void* const* d_in, const int* in_sizes, int n_in,
                              void* d_out, int out_size, void* d_ws, size_t ws_size,
                              hipStream_t stream) {
  Params p;
  p.gt  = (const float*)d_in[0];
  p.gtn = (const float*)d_in[1];
  for (int i=0;i<3;i++){
    p.pred[i]  = (const float*)d_in[2+5*i];
    p.bef[i]   = (const float*)d_in[3+5*i];
    p.edges[i] = (const int*)  d_in[4+5*i];
    p.faces[i] = (const int*)  d_in[5+5*i];
    p.lap[i]   = (const int*)  d_in[6+5*i];
    p.v[i] = in_sizes[2+5*i]/3;
    p.E[i] = in_sizes[4+5*i]/2;
    p.F[i] = in_sizes[5+5*i]/3;
    p.M[i] = p.v[i] + NSAMP;
  }
  // Workspace layout (~395 KB total; words):
  //   [0,32)  acc  (zeroed)
  //   [32]    counter (zeroed; zero-region = first 64 words)
  //   [64..)  mb1[3] | mb2a[3] | mb2b[3]   (0xFF-filled)
  //   then    S[3]  (written by prep, no init)
  unsigned int* base = (unsigned int*)d_ws;
  p.acc = (float*)base;
  p.counter = base + 32;
  p.init_base = base;
  unsigned int* w = base + 64;
  for (int i=0;i<3;i++){ p.mb1[i]  = w; w += NGT; }
  for (int i=0;i<3;i++){ p.mb2a[i] = (unsigned long long*)w; w += 2*p.v[i]; }
  for (int i=0;i<3;i++){ p.mb2b[i] = w; w += NSAMP; }
  p.init_words = (int)(w - base);
  for (int i=0;i<3;i++){ p.S[i] = (float*)w; w += NSAMP*3; }

  int maxM = p.M[0], maxE = p.E[0], maxV = p.v[0];
  for (int i=1;i<3;i++){
    if (p.M[i]>maxM) maxM=p.M[i];
    if (p.E[i]>maxE) maxE=p.E[i];
    if (p.v[i]>maxV) maxV=p.v[i];
  }
  int Z1 = (maxM + CH-1)/CH;
  int Z2 = (NGT + CH-1)/CH;
  p.z1 = Z1; p.z2 = Z2;
  int gx1 = (NGT + QB-1)/QB;    // dist1 queries
  int gx2 = (maxV + QB-1)/QB;   // dist2-pred queries
  int gx3 = (NSAMP + QB-1)/QB;  // dist2-samp queries
  int gxB = gx1;
  if (gx2 > gxB) gxB = gx2;
  if (gx3 > gxB) gxB = gx3;

  int gxA = (p.init_words + 255)/256;           // init blocks (also covers sampling: 16 < gxA)
  int gxC = (maxE + 255)/256;                   // E = 3v dominates all roles

  prep_kernel   <<<dim3(gxA, 3, 2),        256, 0, stream>>>(p);
  chamfer_kernel<<<dim3(gxB, 3, Z1+2*Z2),  256, 0, stream>>>(p);
  finish_kernel <<<dim3(gxC, 3, 4),        256, 0, stream>>>(p, (float*)d_out);
}

// Round 9
// 184.192 us; speedup vs baseline: 1.1609x; 1.1609x over previous
//
#include <hip/hip_runtime.h>
#include <stdint.h>

#define NGT 8000
#define NSAMP 4000
#define QT 4        // queries per thread (register tile)
#define QB 1024     // queries per block (256 threads * QT)
#define CH 384      // scanned-points chunk per blockIdx.z (even)

struct Params {
  const float* gt;        // (8000,3)
  const float* gtn;       // (8000,3)
  const float* pred[3];   // (v,3)
  const float* bef[3];    // (v,3)
  const int*   edges[3];  // (3v,2)
  const int*   faces[3];  // (2v,3)
  const int*   lap[3];    // (v,10)
  float* S[3];            // (4000,3) sampled surface points
  unsigned int* mb1[3];        // (8000) ordered-float min bits (dist1)
  unsigned long long* mb2a[3]; // (v) packed (ordered dist << 32 | gt idx) for pred queries
  unsigned int* mb2b[3];       // (4000) ordered-float min bits for sample queries
  float* acc;             // per mesh i: [8i]=sum_d1 [8i+1]=sum_d2 [8i+2]=sum|dot| [8i+3]=edge_sq [8i+4]=lap_sq [8i+5]=move_sq
  unsigned int* counter;  // finish_kernel block-completion counter
  unsigned int* init_base;// = (u32*)d_ws
  int init_words;         // words to initialize (first 64 -> 0, rest -> 0xFF)
  int v[3], M[3], E[3], F[3];
  int z1, z2;             // chunk counts: dist1 z in [0,z1); dist2-pred [z1,z1+z2); dist2-samp [z1+z2,z1+2*z2)
};

// ---- ordered-float <-> uint (monotone, atomicMin-compatible) ----
__device__ __forceinline__ unsigned int ford(float f){
  unsigned int b = __float_as_uint(f);
  return b ^ ((b >> 31) ? 0xFFFFFFFFu : 0x80000000u);
}
__device__ __forceinline__ float funord(unsigned int u){
  unsigned int b = u ^ ((u >> 31) ? 0x80000000u : 0xFFFFFFFFu);
  return __uint_as_float(b);
}

// ---------------- threefry2x32 (exact JAX) ----------------
__device__ __forceinline__ uint32_t rotl32(uint32_t x, int d){ return (x<<d)|(x>>(32-d)); }

__device__ __forceinline__ void tf2x32(uint32_t k0, uint32_t k1, uint32_t c0, uint32_t c1,
                                       uint32_t& o0, uint32_t& o1){
  uint32_t ks2 = k0 ^ k1 ^ 0x1BD11BDAu;
  uint32_t x0 = c0 + k0, x1 = c1 + k1;
  x0+=x1; x1=rotl32(x1,13); x1^=x0;
  x0+=x1; x1=rotl32(x1,15); x1^=x0;
  x0+=x1; x1=rotl32(x1,26); x1^=x0;
  x0+=x1; x1=rotl32(x1, 6); x1^=x0;
  x0+=k1; x1+=ks2+1u;
  x0+=x1; x1=rotl32(x1,17); x1^=x0;
  x0+=x1; x1=rotl32(x1,29); x1^=x0;
  x0+=x1; x1=rotl32(x1,16); x1^=x0;
  x0+=x1; x1=rotl32(x1,24); x1^=x0;
  x0+=ks2; x1+=k0+2u;
  x0+=x1; x1=rotl32(x1,13); x1^=x0;
  x0+=x1; x1=rotl32(x1,15); x1^=x0;
  x0+=x1; x1=rotl32(x1,26); x1^=x0;
  x0+=x1; x1=rotl32(x1, 6); x1^=x0;
  x0+=k0; x1+=k1+3u;
  x0+=x1; x1=rotl32(x1,17); x1^=x0;
  x0+=x1; x1=rotl32(x1,29); x1^=x0;
  x0+=x1; x1=rotl32(x1,16); x1^=x0;
  x0+=x1; x1=rotl32(x1,24); x1^=x0;
  x0+=k1; x1+=ks2+4u;
  x0+=x1; x1=rotl32(x1,13); x1^=x0;
  x0+=x1; x1=rotl32(x1,15); x1^=x0;
  x0+=x1; x1=rotl32(x1,26); x1^=x0;
  x0+=x1; x1=rotl32(x1, 6); x1^=x0;
  x0+=ks2; x1+=k0+5u;
  o0=x0; o1=x1;
}

__device__ __forceinline__ uint32_t rbits(uint32_t k0, uint32_t k1, uint32_t idx, uint32_t total){
  uint32_t half = total>>1, o0, o1;
  if (idx < half){ tf2x32(k0,k1, idx, idx+half, o0, o1); return o0; }
  tf2x32(k0,k1, idx-half, idx, o0, o1); return o1;
}

// ---------------- A: init workspace (z=0,y=0) + sample surface points (z=1) ----------------
__global__ __launch_bounds__(256) void prep_kernel(Params p){
  if (blockIdx.z == 0){
    if (blockIdx.y != 0) return;
    int wdi = blockIdx.x*256 + threadIdx.x;
    if (wdi < p.init_words)
      p.init_base[wdi] = (wdi < 64) ? 0u : 0xFFFFFFFFu;
    return;
  }
  int i = blockIdx.y;
  int s = blockIdx.x*256 + threadIdx.x;
  if (s >= NSAMP) return;
  uint32_t bk0, bk1; tf2x32(0u, 42u, 0u, (uint32_t)i, bk0, bk1);
  uint32_t a0,b0,a1,b1;
  tf2x32(bk0,bk1, 0u,2u, a0,b0);
  tf2x32(bk0,bk1, 1u,3u, a1,b1);
  uint32_t fb = rbits(a0,a1,(uint32_t)s, NSAMP);
  uint32_t fidx = fb % (uint32_t)p.F[i];
  uint32_t u0b = rbits(b0,b1, 2u*(uint32_t)s,    2u*NSAMP);
  uint32_t u1b = rbits(b0,b1, 2u*(uint32_t)s+1u, 2u*NSAMP);
  float u0 = __uint_as_float((u0b>>9)|0x3F800000u) - 1.0f;
  float u1 = __uint_as_float((u1b>>9)|0x3F800000u) - 1.0f;
  float r1 = sqrtf(u0);
  float w0 = 1.0f - r1, w1 = r1*(1.0f-u1), w2 = r1*u1;
  const int* f = p.faces[i] + 3*(int)fidx;
  const float* pr = p.pred[i];
  int va=f[0], vb=f[1], vc=f[2];
  float* dst = p.S[i] + 3*s;
  dst[0] = w0*pr[3*va+0] + w1*pr[3*vb+0] + w2*pr[3*vc+0];
  dst[1] = w0*pr[3*va+1] + w1*pr[3*vb+1] + w2*pr[3*vc+1];
  dst[2] = w0*pr[3*va+2] + w1*pr[3*vb+2] + w2*pr[3*vc+2];
}

// ---------------- B: fused chamfer, 3 roles, chunked + register-tiled ----------------
// logical point set P = pred (v pts) ++ samples (4000 pts).
// z in [0,z1)        : dist1      — queries = gt (8000),  scan P chunk z
// z in [z1,z1+z2)    : dist2-pred — queries = pred (v),   scan gt chunk, track argmin
// z in [z1+z2,z1+2z2): dist2-samp — queries = S (4000),   scan gt chunk, min only
__global__ __launch_bounds__(256) void chamfer_kernel(Params p){
  int i = blockIdx.y;
  int v = p.v[i];
  int M = p.M[i];
  int z = blockIdx.z;
  __shared__ float4 tile[CH];
  int t = threadIdx.x;
  int qbase = blockIdx.x*QB;

  if (z < p.z1){
    // ---- dist1: queries = gt, scan one P chunk ----
    if (qbase >= NGT) return;
    int c0 = z*CH;
    if (c0 >= M) return;
    int c1 = min(M, c0+CH);
    int lim = c1 - c0;

    for (int jj=t; jj<lim; jj+=256){
      int j = c0 + jj;
      const float* src = (j < v) ? (p.pred[i] + 3*j) : (p.S[i] + 3*(j-v));
      float x=src[0], y=src[1], zz=src[2];
      tile[jj] = make_float4(x,y,zz, x*x+y*y+zz*zz);
    }

    float qx[QT], qy[QT], qz[QT], qs[QT], best[QT];
    #pragma unroll
    for (int k=0;k<QT;k++){
      int q = qbase + t + k*256;
      float x=0.f,y=0.f,zz=0.f;
      if (q < NGT){ x=p.gt[3*q]; y=p.gt[3*q+1]; zz=p.gt[3*q+2]; }
      qs[k]=x*x+y*y+zz*zz; qx[k]=-2.f*x; qy[k]=-2.f*y; qz[k]=-2.f*zz;
      best[k]=3.4e38f;
    }
    __syncthreads();

    int lim2 = lim & ~1;
    #pragma unroll 2
    for (int k=0;k<lim2;k+=2){
      float4 g0 = tile[k];
      float4 g1 = tile[k+1];
      #pragma unroll
      for (int q=0;q<QT;q++){
        float d0 = fmaf(g0.x,qx[q], fmaf(g0.y,qy[q], fmaf(g0.z,qz[q], g0.w)));
        float d1 = fmaf(g1.x,qx[q], fmaf(g1.y,qy[q], fmaf(g1.z,qz[q], g1.w)));
        best[q] = fminf(fminf(best[q], d0), d1);   // -> v_min3_f32
      }
    }
    if (lim2 < lim){
      float4 g0 = tile[lim2];
      #pragma unroll
      for (int q=0;q<QT;q++){
        float d0 = fmaf(g0.x,qx[q], fmaf(g0.y,qy[q], fmaf(g0.z,qz[q], g0.w)));
        best[q] = fminf(best[q], d0);
      }
    }
    #pragma unroll
    for (int k=0;k<QT;k++){
      int q = qbase + t + k*256;
      if (q < NGT) atomicMin(&p.mb1[i][q], ford(best[k]+qs[k]));
    }
  } else if (z < p.z1 + p.z2){
    // ---- dist2-pred: queries = pred, scan one gt chunk, argmin tracked ----
    if (qbase >= v) return;
    int c0 = (z - p.z1)*CH;
    int c1 = min(NGT, c0+CH);
    int lim = c1 - c0;

    for (int jj=t; jj<lim; jj+=256){
      int j = c0 + jj;
      float x=p.gt[3*j], y=p.gt[3*j+1], zz=p.gt[3*j+2];
      tile[jj] = make_float4(x,y,zz, x*x+y*y+zz*zz);
    }

    float qx[QT], qy[QT], qz[QT], qs[QT], best[QT];
    int bidx[QT];
    #pragma unroll
    for (int k=0;k<QT;k++){
      int q = qbase + t + k*256;
      float x=0.f,y=0.f,zz=0.f;
      if (q < v){
        const float* src = p.pred[i] + 3*q;
        x=src[0]; y=src[1]; zz=src[2];
      }
      qs[k]=x*x+y*y+zz*zz; qx[k]=-2.f*x; qy[k]=-2.f*y; qz[k]=-2.f*zz;
      best[k]=3.4e38f; bidx[k]=0;
    }
    __syncthreads();

    #pragma unroll 4
    for (int k=0;k<lim;k++){
      float4 g = tile[k];
      #pragma unroll
      for (int q=0;q<QT;q++){
        float d = fmaf(g.x,qx[q], fmaf(g.y,qy[q], fmaf(g.z,qz[q], g.w)));
        if (d < best[q]){ best[q]=d; bidx[q]=c0+k; }   // ascending scan: first min
      }
    }
    #pragma unroll
    for (int k=0;k<QT;k++){
      int q = qbase + t + k*256;
      if (q < v){
        unsigned long long pk = ((unsigned long long)ford(best[k]+qs[k])<<32) | (unsigned int)bidx[k];
        atomicMin(&p.mb2a[i][q], pk);   // equal dist -> smaller gt idx = first occurrence
      }
    }
  } else {
    // ---- dist2-samp: queries = S (their argmin is never consumed) ----
    if (qbase >= NSAMP) return;
    int c0 = (z - p.z1 - p.z2)*CH;
    int c1 = min(NGT, c0+CH);
    int lim = c1 - c0;

    for (int jj=t; jj<lim; jj+=256){
      int j = c0 + jj;
      float x=p.gt[3*j], y=p.gt[3*j+1], zz=p.gt[3*j+2];
      tile[jj] = make_float4(x,y,zz, x*x+y*y+zz*zz);
    }

    float qx[QT], qy[QT], qz[QT], qs[QT], best[QT];
    #pragma unroll
    for (int k=0;k<QT;k++){
      int q = qbase + t + k*256;
      float x=0.f,y=0.f,zz=0.f;
      if (q < NSAMP){
        const float* src = p.S[i] + 3*q;
        x=src[0]; y=src[1]; zz=src[2];
      }
      qs[k]=x*x+y*y+zz*zz; qx[k]=-2.f*x; qy[k]=-2.f*y; qz[k]=-2.f*zz;
      best[k]=3.4e38f;
    }
    __syncthreads();

    int lim2 = lim & ~1;
    #pragma unroll 2
    for (int k=0;k<lim2;k+=2){
      float4 g0 = tile[k];
      float4 g1 = tile[k+1];
      #pragma unroll
      for (int q=0;q<QT;q++){
        float d0 = fmaf(g0.x,qx[q], fmaf(g0.y,qy[q], fmaf(g0.z,qz[q], g0.w)));
        float d1 = fmaf(g1.x,qx[q], fmaf(g1.y,qy[q], fmaf(g1.z,qz[q], g1.w)));
        best[q] = fminf(fminf(best[q], d0), d1);   // -> v_min3_f32
      }
    }
    if (lim2 < lim){
      float4 g0 = tile[lim2];
      #pragma unroll
      for (int q=0;q<QT;q++){
        float d0 = fmaf(g0.x,qx[q], fmaf(g0.y,qy[q], fmaf(g0.z,qz[q], g0.w)));
        best[q] = fminf(best[q], d0);
      }
    }
    #pragma unroll
    for (int k=0;k<QT;k++){
      int q = qbase + t + k*256;
      if (q < NSAMP) atomicMin(&p.mb2b[i][q], ford(best[k]+qs[k]));
    }
  }
}

// ---------------- C: all reductions + losses + last-block finalize ----------------
// z=0: dist2 sum over M; z=1: dist1 sum over NGT; z=2: edge+normal over E; z=3: lap+move over v
__global__ __launch_bounds__(256) void finish_kernel(Params p, float* out){
  __shared__ float red[256];
  int i = blockIdx.y;
  int z = blockIdx.z;
  int tid = threadIdx.x;
  int gidx = blockIdx.x*256 + tid;

  if (z == 0){
    int M = p.M[i], v = p.v[i];
    float val = 0.f;
    if (gidx < M){
      if (gidx < v) val = funord((unsigned int)(p.mb2a[i][gidx]>>32));
      else          val = funord(p.mb2b[i][gidx-v]);
    }
    red[tid] = val; __syncthreads();
    for (int s=128;s>0;s>>=1){ if (tid<s) red[tid]+=red[tid+s]; __syncthreads(); }
    if (tid==0 && red[0]!=0.f) atomicAdd(&p.acc[8*i+1], red[0]);
  } else if (z == 1){
    float val = 0.f;
    if (gidx < NGT) val = funord(p.mb1[i][gidx]);
    red[tid] = val; __syncthreads();
    for (int s=128;s>0;s>>=1){ if (tid<s) red[tid]+=red[tid+s]; __syncthreads(); }
    if (tid==0 && red[0]!=0.f) atomicAdd(&p.acc[8*i+0], red[0]);
  } else if (z == 2){
    int E = p.E[i];
    float sq = 0.f, ad = 0.f;
    if (gidx < E){
      int e0 = p.edges[i][2*gidx], e1 = p.edges[i][2*gidx+1];
      const float* pr = p.pred[i];
      float dx = pr[3*e0+0]-pr[3*e1+0];
      float dy = pr[3*e0+1]-pr[3*e1+1];
      float dz = pr[3*e0+2]-pr[3*e1+2];
      sq = dx*dx+dy*dy+dz*dz;
      float inv = 1.0f / fmaxf(sqrtf(sq), 1e-12f);
      int g = (int)(unsigned int)p.mb2a[i][e0];   // argmin gt index (low 32 bits)
      float nx = p.gtn[3*g+0], ny = p.gtn[3*g+1], nz = p.gtn[3*g+2];
      float invg = 1.0f / fmaxf(sqrtf(nx*nx+ny*ny+nz*nz), 1e-12f);
      ad = fabsf((dx*nx+dy*ny+dz*nz)*inv*invg);
    }
    red[tid] = ad; __syncthreads();
    for (int s=128;s>0;s>>=1){ if (tid<s) red[tid]+=red[tid+s]; __syncthreads(); }
    if (tid==0 && red[0]!=0.f) atomicAdd(&p.acc[8*i+2], red[0]);
    __syncthreads();
    red[tid] = sq; __syncthreads();
    for (int s=128;s>0;s>>=1){ if (tid<s) red[tid]+=red[tid+s]; __syncthreads(); }
    if (tid==0 && red[0]!=0.f) atomicAdd(&p.acc[8*i+3], red[0]);
  } else {
    int v = p.v[i];
    float lsq = 0.f, msq = 0.f;
    if (gidx < v){
      const int* L = p.lap[i] + 10*gidx;
      const float* B = p.bef[i];
      const float* R = p.pred[i];
      float cnt = (float)L[9];
      float sb0=0,sb1=0,sb2=0, sp0=0,sp1=0,sp2=0;
      #pragma unroll
      for (int k=0;k<8;k++){
        int id = L[k];
        if (id >= 0){
          sb0 += B[3*id+0]; sb1 += B[3*id+1]; sb2 += B[3*id+2];
          sp0 += R[3*id+0]; sp1 += R[3*id+1]; sp2 += R[3*id+2];
        }
      }
      float lb0 = B[3*gidx+0] - sb0/cnt, lb1 = B[3*gidx+1] - sb1/cnt, lb2 = B[3*gidx+2] - sb2/cnt;
      float lp0 = R[3*gidx+0] - sp0/cnt, lp1 = R[3*gidx+1] - sp1/cnt, lp2 = R[3*gidx+2] - sp2/cnt;
      float d0=lb0-lp0, d1=lb1-lp1, d2=lb2-lp2;
      lsq = d0*d0+d1*d1+d2*d2;
      float m0=B[3*gidx+0]-R[3*gidx+0], m1=B[3*gidx+1]-R[3*gidx+1], m2=B[3*gidx+2]-R[3*gidx+2];
      msq = m0*m0+m1*m1+m2*m2;
    }
    red[tid] = lsq; __syncthreads();
    for (int s=128;s>0;s>>=1){ if (tid<s) red[tid]+=red[tid+s]; __syncthreads(); }
    if (tid==0 && red[0]!=0.f) atomicAdd(&p.acc[8*i+4], red[0]);
    __syncthreads();
    red[tid] = msq; __syncthreads();
    for (int s=128;s>0;s>>=1){ if (tid<s) red[tid]+=red[tid+s]; __syncthreads(); }
    if (tid==0 && red[0]!=0.f) atomicAdd(&p.acc[8*i+5], red[0]);
  }

  __syncthreads();
  if (tid == 0){
    __threadfence();
    unsigned int total = gridDim.x*gridDim.y*gridDim.z;
    unsigned int old = atomicAdd(p.counter, 1u);
    if (old == total-1){
      __threadfence();
      const float CHAMW[3] = {3000.0f, 3000.0f, 3000.0f};
      const float LAPC[3]  = {0.2f, 1.0f, 1.0f};
      float loss = 0.0f;
      for (int m=0;m<3;m++){
        float a0 = __hip_atomic_load(&p.acc[8*m+0], __ATOMIC_RELAXED, __HIP_MEMORY_SCOPE_AGENT);
        float a1 = __hip_atomic_load(&p.acc[8*m+1], __ATOMIC_RELAXED, __HIP_MEMORY_SCOPE_AGENT);
        float a2 = __hip_atomic_load(&p.acc[8*m+2], __ATOMIC_RELAXED, __HIP_MEMORY_SCOPE_AGENT);
        float a3 = __hip_atomic_load(&p.acc[8*m+3], __ATOMIC_RELAXED, __HIP_MEMORY_SCOPE_AGENT);
        float a4 = __hip_atomic_load(&p.acc[8*m+4], __ATOMIC_RELAXED, __HIP_MEMORY_SCOPE_AGENT);
        float a5 = __hip_atomic_load(&p.acc[8*m+5], __ATOMIC_RELAXED, __HIP_MEMORY_SCOPE_AGENT);
        float ch = CHAMW[m]*(a0/(float)NGT + 0.55f*a1/(float)p.M[m]);
        float nl = a2/(float)p.E[m];
        float el = a3/(float)p.E[m];
        float ll = LAPC[m]*a4/(float)p.v[m];
        float ml = (m>0) ? LAPC[m]*a5/(float)p.v[m] : 0.0f;
        loss += ch + 1500.0f*ll + 50.0f*ml + 359.0f*el + 0.5f*nl;
      }
      out[0] = loss;
    }
  }
}

extern "C" void kernel_launch(void* const* d_in, const int* in_sizes, int n_in,
                              void* d_out, int out_size, void* d_ws, size_t ws_size,
                              hipStream_t stream) {
  Params p;
  p.gt  = (const float*)d_in[0];
  p.gtn = (const float*)d_in[1];
  for (int i=0;i<3;i++){
    p.pred[i]  = (const float*)d_in[2+5*i];
    p.bef[i]   = (const float*)d_in[3+5*i];
    p.edges[i] = (const int*)  d_in[4+5*i];
    p.faces[i] = (const int*)  d_in[5+5*i];
    p.lap[i]   = (const int*)  d_in[6+5*i];
    p.v[i] = in_sizes[2+5*i]/3;
    p.E[i] = in_sizes[4+5*i]/2;
    p.F[i] = in_sizes[5+5*i]/3;
    p.M[i] = p.v[i] + NSAMP;
  }
  // Workspace layout (~395 KB total; words):
  //   [0,32)  acc  (zeroed)
  //   [32]    counter (zeroed; zero-region = first 64 words)
  //   [64..)  mb1[3] | mb2a[3] | mb2b[3]   (0xFF-filled)
  //   then    S[3]  (written by prep, no init)
  unsigned int* base = (unsigned int*)d_ws;
  p.acc = (float*)base;
  p.counter = base + 32;
  p.init_base = base;
  unsigned int* w = base + 64;
  for (int i=0;i<3;i++){ p.mb1[i]  = w; w += NGT; }
  for (int i=0;i<3;i++){ p.mb2a[i] = (unsigned long long*)w; w += 2*p.v[i]; }
  for (int i=0;i<3;i++){ p.mb2b[i] = w; w += NSAMP; }
  p.init_words = (int)(w - base);
  for (int i=0;i<3;i++){ p.S[i] = (float*)w; w += NSAMP*3; }

  int maxM = p.M[0], maxE = p.E[0], maxV = p.v[0];
  for (int i=1;i<3;i++){
    if (p.M[i]>maxM) maxM=p.M[i];
    if (p.E[i]>maxE) maxE=p.E[i];
    if (p.v[i]>maxV) maxV=p.v[i];
  }
  int Z1 = (maxM + CH-1)/CH;
  int Z2 = (NGT + CH-1)/CH;
  p.z1 = Z1; p.z2 = Z2;
  int gx1 = (NGT + QB-1)/QB;    // dist1 queries
  int gx2 = (maxV + QB-1)/QB;   // dist2-pred queries
  int gx3 = (NSAMP + QB-1)/QB;  // dist2-samp queries
  int gxB = gx1;
  if (gx2 > gxB) gxB = gx2;
  if (gx3 > gxB) gxB = gx3;

  int gxA = (p.init_words + 255)/256;           // init blocks (also covers sampling: 16 < gxA)
  int gxC = (maxE + 255)/256;                   // E = 3v dominates all roles

  prep_kernel   <<<dim3(gxA, 3, 2),        256, 0, stream>>>(p);
  chamfer_kernel<<<dim3(gxB, 3, Z1+2*Z2),  256, 0, stream>>>(p);
  finish_kernel <<<dim3(gxC, 3, 4),        256, 0, stream>>>(p, (float*)d_out);
}